// Round 2
// baseline (364.930 us; speedup 1.0000x reference)
//
#include <hip/hip_runtime.h>
#include <math.h>

// NetVLAD on MI355X, fp32 vector path (no fp32 MFMA on CDNA4).
// N=128 images, C=256 channels, K=64 clusters, P=1024 pixels.

#define C_DIM 256
#define K_CL  64
#define P_PIX 1024
#define CHUNK 256          // pixels per block (4 chunks per image)
#define SUB   32           // pixels per GEMM subtile
#define XS_LD 268          // pad: 16B-aligned rows, 4-way max write conflict
#define A_LD  68           // pad for a-tile

// ws layout (floats): [0,16384) = WT[c][k]; [16384, 16384+128*64) = asum[n][k]

__global__ void transpose_w(const float* __restrict__ w, float* __restrict__ wt) {
    int idx = blockIdx.x * 256 + threadIdx.x;   // 64 blocks -> 16384 elems
    int c = idx >> 6, k = idx & 63;
    wt[idx] = w[k * C_DIM + c];                 // WT[c*64 + k] = W[k][c]
}

__global__ __launch_bounds__(256, 2) void netvlad_main(
    const float* __restrict__ x, const float* __restrict__ wt,
    const float* __restrict__ bias, float* __restrict__ out,
    float* __restrict__ asum_g) {
    __shared__ float xs[SUB][XS_LD];     // xnorm subtile, [p][c]
    __shared__ float a_lds[SUB][A_LD];   // softmax subtile, [p][k]
    __shared__ float rn_lds[CHUNK];      // per-pixel inverse norms

    const int t = threadIdx.x;
    const int n = blockIdx.x >> 2;
    const int chunk = blockIdx.x & 3;
    const size_t ximg = (size_t)n * C_DIM * P_PIX;
    const int p = chunk * CHUNK + t;          // this thread's pixel
    const float* xp = x + ximg + p;           // stride P_PIX over c

    // ---- Phase L: stream x once; raw logits (64 accums) + sum of squares.
    // Software-pipelined: prefetch 4 c-iterations ahead so the strided
    // global loads overlap ~260 FMA instructions.
    float lg[K_CL];
    #pragma unroll
    for (int k = 0; k < K_CL; ++k) lg[k] = 0.f;
    float ss = 0.f;

    float xv[4];
    #pragma unroll
    for (int i = 0; i < 4; ++i) xv[i] = xp[(size_t)i * P_PIX];

    for (int c = 0; c < C_DIM - 4; c += 4) {
        float nx[4];
        #pragma unroll
        for (int i = 0; i < 4; ++i) nx[i] = xp[(size_t)(c + 4 + i) * P_PIX];
        #pragma unroll
        for (int i = 0; i < 4; ++i) {
            const float v = xv[i];
            ss = fmaf(v, v, ss);
            const float* wr = wt + (c + i) * K_CL;   // wave-uniform -> s_load
            #pragma unroll
            for (int k = 0; k < K_CL; ++k) lg[k] = fmaf(wr[k], v, lg[k]);
        }
        #pragma unroll
        for (int i = 0; i < 4; ++i) xv[i] = nx[i];
    }
    #pragma unroll
    for (int i = 0; i < 4; ++i) {     // tail: c = 252..255
        const float v = xv[i];
        ss = fmaf(v, v, ss);
        const float* wr = wt + (C_DIM - 4 + i) * K_CL;
        #pragma unroll
        for (int k = 0; k < K_CL; ++k) lg[k] = fmaf(wr[k], v, lg[k]);
    }

    const float rn = 1.f / fmaxf(sqrtf(ss), 1e-12f);
    rn_lds[t] = rn;

    // ---- softmax fully in-register (normalize folded in: logit = raw*rn + b)
    float mx = -3.402823466e38f;
    #pragma unroll
    for (int k = 0; k < K_CL; ++k) {
        lg[k] = fmaf(lg[k], rn, bias[k]);
        mx = fmaxf(mx, lg[k]);
    }
    float den = 0.f;
    #pragma unroll
    for (int k = 0; k < K_CL; ++k) { lg[k] = __expf(lg[k] - mx); den += lg[k]; }
    const float inv = 1.f / den;
    #pragma unroll
    for (int k = 0; k < K_CL; ++k) lg[k] *= inv;   // lg[] is now a[k]

    // ---- Phase G: agg[k][c] += a[k][p] * xn[c][p] over this block's 256 pixels.
    float acc[8][8];
    #pragma unroll
    for (int i = 0; i < 8; ++i)
        #pragma unroll
        for (int j = 0; j < 8; ++j) acc[i][j] = 0.f;
    float asum_r = 0.f;
    const int k0 = (t >> 5) * 8;   // 8 k-rows per thread
    const int c0 = (t & 31) * 8;   // 8 c-cols per thread

    // staging mapping: coalesced — 32 consecutive lanes read 32 consecutive
    // pixels at fixed c (128B segments), 32 independent dword loads/thread.
    const int spp  = t & 31;        // pixel-in-subtile this thread stages
    const int cb   = t >> 5;        // c = cb + 8*i, i = 0..31

    __syncthreads();  // rn_lds ready

    for (int sub = 0; sub < 8; ++sub) {
        // owning threads (pixels of this subtile) publish their a[]
        if ((t >> 5) == sub) {
            const int pr = t & 31;
            #pragma unroll
            for (int k = 0; k < K_CL; k += 4) {
                float4 v; v.x = lg[k]; v.y = lg[k+1]; v.z = lg[k+2]; v.w = lg[k+3];
                *(float4*)&a_lds[pr][k] = v;
            }
        }
        // cooperative, coalesced re-load of x subtile (L2/L3-hot),
        // scale by rn, store transposed to [p][c]
        {
            const float rnp = rn_lds[sub * SUB + spp];
            const float* src = x + ximg + (size_t)chunk * CHUNK + sub * SUB + spp;
            #pragma unroll
            for (int i = 0; i < 32; ++i) {
                const int c = cb + i * 8;
                xs[spp][c] = src[(size_t)c * P_PIX] * rnp;
            }
        }
        __syncthreads();

        for (int pp = 0; pp < SUB; ++pp) {
            const float4 a0 = *(const float4*)&a_lds[pp][k0];
            const float4 a1 = *(const float4*)&a_lds[pp][k0+4];
            const float4 x0 = *(const float4*)&xs[pp][c0];
            const float4 x1 = *(const float4*)&xs[pp][c0+4];
            const float av[8] = {a0.x,a0.y,a0.z,a0.w,a1.x,a1.y,a1.z,a1.w};
            const float xv8[8] = {x0.x,x0.y,x0.z,x0.w,x1.x,x1.y,x1.z,x1.w};
            #pragma unroll
            for (int i = 0; i < 8; ++i)
                #pragma unroll
                for (int j = 0; j < 8; ++j)
                    acc[i][j] = fmaf(av[i], xv8[j], acc[i][j]);
        }
        if (t < K_CL) {   // asum partial from the staged a tile
            #pragma unroll
            for (int pp = 0; pp < SUB; ++pp) asum_r += a_lds[pp][t];
        }
        __syncthreads();
    }

    // ---- publish partials (4 writers per cell)
    float* op = out + (size_t)n * K_CL * C_DIM;
    #pragma unroll
    for (int i = 0; i < 8; ++i)
        #pragma unroll
        for (int j = 0; j < 8; ++j)
            atomicAdd(&op[(k0 + i) * C_DIM + c0 + j], acc[i][j]);
    if (t < K_CL) atomicAdd(&asum_g[n * K_CL + t], asum_r);
}

__global__ __launch_bounds__(256) void netvlad_epi(
    float* __restrict__ out, const float* __restrict__ asum_g,
    const float* __restrict__ cent) {
    __shared__ float wred[4];
    __shared__ float gs_sh;
    const int n = blockIdx.x;
    const int t = threadIdx.x;
    const int k = t >> 2;          // 4 threads per cluster row
    const int q = t & 3;
    float* op = out + (size_t)n * 16384 + k * 256 + q * 64;
    const float* cp = cent + k * 256 + q * 64;
    const float as = asum_g[n * 64 + k];

    float v[64];
    float ss = 0.f;
    #pragma unroll
    for (int i = 0; i < 64; i += 4) {
        const float4 av = *(const float4*)&op[i];
        const float4 cv = *(const float4*)&cp[i];
        v[i+0] = fmaf(-as, cv.x, av.x);
        v[i+1] = fmaf(-as, cv.y, av.y);
        v[i+2] = fmaf(-as, cv.z, av.z);
        v[i+3] = fmaf(-as, cv.w, av.w);
        ss = fmaf(v[i+0], v[i+0], ss);
        ss = fmaf(v[i+1], v[i+1], ss);
        ss = fmaf(v[i+2], v[i+2], ss);
        ss = fmaf(v[i+3], v[i+3], ss);
    }
    // intra-norm: reduce over the 4 lanes sharing k
    ss += __shfl_xor(ss, 1);
    ss += __shfl_xor(ss, 2);
    const float iscale = 1.f / fmaxf(sqrtf(ss), 1e-12f);

    // global norm: sum of ss*iscale^2 over distinct k rows
    float g = (q == 0) ? ss * iscale * iscale : 0.f;
    #pragma unroll
    for (int off = 4; off < 64; off <<= 1) g += __shfl_xor(g, off);
    if ((t & 63) == 0) wred[t >> 6] = g;
    __syncthreads();
    if (t == 0) {
        const float tot = wred[0] + wred[1] + wred[2] + wred[3];
        gs_sh = 1.f / fmaxf(sqrtf(tot), 1e-12f);
    }
    __syncthreads();
    const float fs = iscale * gs_sh;
    #pragma unroll
    for (int i = 0; i < 64; i += 4) {
        float4 w4;
        w4.x = v[i+0] * fs; w4.y = v[i+1] * fs;
        w4.z = v[i+2] * fs; w4.w = v[i+3] * fs;
        *(float4*)&op[i] = w4;
    }
}

extern "C" void kernel_launch(void* const* d_in, const int* in_sizes, int n_in,
                              void* d_out, int out_size, void* d_ws, size_t ws_size,
                              hipStream_t stream) {
    (void)in_sizes; (void)n_in; (void)ws_size;
    const float* x    = (const float*)d_in[0];
    const float* w    = (const float*)d_in[1];
    const float* b    = (const float*)d_in[2];
    const float* cent = (const float*)d_in[3];
    float* out = (float*)d_out;
    float* wt     = (float*)d_ws;          // 16384 floats
    float* asum_g = wt + 16384;            // 8192 floats

    hipMemsetAsync(d_out, 0, (size_t)out_size * sizeof(float), stream);
    hipMemsetAsync(asum_g, 0, 128 * 64 * sizeof(float), stream);
    transpose_w<<<64, 256, 0, stream>>>(w, wt);
    netvlad_main<<<512, 256, 0, stream>>>(x, wt, b, out, asum_g);
    netvlad_epi<<<128, 256, 0, stream>>>(out, asum_g, cent);
}

// Round 3
// 160.169 us; speedup vs baseline: 2.2784x; 2.2784x over previous
//
#include <hip/hip_runtime.h>
#include <math.h>

// NetVLAD on MI355X via bf16 hi/lo-split MFMA (3-product emulated fp32).
// N=128 images, C=256 channels, K=64 clusters, P=1024 pixels.
// Block = (image, quarter): 256 pixels, 512 threads = 8 waves.
// GEMM1: logits[64k x 256p] = W[64k x 256c] @ x[256c x 256p]   (raw x; rn folded later)
// GEMM2: agg[64k x 256c]   += a[64k x 256p] @ (x*rn)^T[256p x 256c]
// MFMA 16x16x32 bf16: A row=lane&15, k=(lane>>4)*8+j; B col=lane&15, same k;
//                     C col=lane&15, row=(lane>>4)*4+reg   (guide-verified C layout)

#define EPSF 1e-12f

typedef __attribute__((ext_vector_type(8))) __bf16 bf16x8;
typedef __attribute__((ext_vector_type(4))) float f32x4;
typedef __attribute__((ext_vector_type(4))) unsigned int u32x4;

#define MFMA(a, b, c) __builtin_amdgcn_mfma_f32_16x16x32_bf16((a), (b), (c), 0, 0, 0)

__device__ __forceinline__ bf16x8 as_bf(u32x4 v) { return __builtin_bit_cast(bf16x8, v); }

// truncation split: x = hi + lo + O(2^-16 |x|), hi/lo bf16 (packed pairs)
__device__ __forceinline__ void split8(const float* xv, u32x4& hi, u32x4& lo) {
    unsigned uh[8], ul[8];
    #pragma unroll
    for (int j = 0; j < 8; ++j) {
        const unsigned u = __float_as_uint(xv[j]);
        uh[j] = u;
        const float hif = __uint_as_float(u & 0xFFFF0000u);
        ul[j] = __float_as_uint(xv[j] - hif);
    }
    #pragma unroll
    for (int w = 0; w < 4; ++w) {
        hi[w] = (uh[2*w+1] & 0xFFFF0000u) | (uh[2*w] >> 16);
        lo[w] = (ul[2*w+1] & 0xFFFF0000u) | (ul[2*w] >> 16);
    }
}

__global__ __launch_bounds__(512, 1) void netvlad_mfma(
    const float* __restrict__ x, const float* __restrict__ wmat,
    const float* __restrict__ bias, float* __restrict__ out,
    float* __restrict__ asum_g) {

    __shared__ __align__(16) unsigned int buf[64 * 260];   // logits f32 -> packed a
    __shared__ __align__(16) float rn_lds[256];
    __shared__ float bias_lds[64];
    float* buf_f = (float*)buf;

    const int t = threadIdx.x;
    const int w = t >> 6, l = t & 63;
    const int l15 = l & 15, lg4 = l >> 4;
    const int n = blockIdx.x >> 2, q = blockIdx.x & 3;
    const size_t ximg = (size_t)n * 256 * 1024;
    const int pbase = q * 256;
    const int mt = w & 3, k0 = mt * 16;
    const int nt0 = (w >> 2) * 8;
    const int cs = lg4 * 8;               // k-slice base within a 32-wide K-step

    if (t < 64) bias_lds[t] = bias[t];

    // ---- W fragments (GEMM1 A), loaded once into registers: 64 VGPRs
    u32x4 whi[8], wlo[8];
    {
        const float* wr = wmat + (k0 + l15) * 256 + cs;
        #pragma unroll
        for (int ks = 0; ks < 8; ++ks) {
            float xv[8];
            const float4 f0 = *(const float4*)(wr + ks * 32);
            const float4 f1 = *(const float4*)(wr + ks * 32 + 4);
            xv[0]=f0.x; xv[1]=f0.y; xv[2]=f0.z; xv[3]=f0.w;
            xv[4]=f1.x; xv[5]=f1.y; xv[6]=f1.z; xv[7]=f1.w;
            split8(xv, whi[ks], wlo[ks]);
        }
    }

    // ---- GEMM1: raw logits
    f32x4 acc[8];
    #pragma unroll
    for (int i = 0; i < 8; ++i) acc[i] = f32x4{0.f, 0.f, 0.f, 0.f};
    float ssp[8];
    #pragma unroll
    for (int i = 0; i < 8; ++i) ssp[i] = 0.f;
    const bool ss_wave = (mt == 0);       // waves 0,4: also accumulate sum(x^2)

    for (int ks = 0; ks < 8; ++ks) {
        #pragma unroll
        for (int ntl = 0; ntl < 8; ++ntl) {
            // B frag: x[c = ks*32+cs+j][p = pbase + nt*16 + l15], 8 strided dwords
            const float* bp = x + ximg + (size_t)(ks * 32 + cs) * 1024
                              + pbase + (nt0 + ntl) * 16 + l15;
            float xv[8];
            #pragma unroll
            for (int j = 0; j < 8; ++j) xv[j] = bp[(size_t)j * 1024];
            if (ss_wave) {
                #pragma unroll
                for (int j = 0; j < 8; ++j) ssp[ntl] = fmaf(xv[j], xv[j], ssp[ntl]);
            }
            u32x4 bhi, blo; split8(xv, bhi, blo);
            acc[ntl] = MFMA(as_bf(whi[ks]), as_bf(bhi), acc[ntl]);
            acc[ntl] = MFMA(as_bf(whi[ks]), as_bf(blo), acc[ntl]);
            acc[ntl] = MFMA(as_bf(wlo[ks]), as_bf(bhi), acc[ntl]);
        }
    }

    // write raw logits to LDS (stride 260: conflict-free for all phases)
    #pragma unroll
    for (int ntl = 0; ntl < 8; ++ntl) {
        const int pp = (nt0 + ntl) * 16 + l15;
        #pragma unroll
        for (int r = 0; r < 4; ++r)
            buf_f[(k0 + lg4 * 4 + r) * 260 + pp] = acc[ntl][r];
    }
    // rn[p] = 1/max(sqrt(ss),eps): reduce 4 lane-groups, waves 0 & 4 cover all 256 p
    if (ss_wave) {
        #pragma unroll
        for (int ntl = 0; ntl < 8; ++ntl) {
            float s = ssp[ntl];
            s += __shfl_xor(s, 16);
            s += __shfl_xor(s, 32);
            if (l < 16) rn_lds[(nt0 + ntl) * 16 + l] = 1.f / fmaxf(sqrtf(s), EPSF);
        }
    }
    __syncthreads();

    // ---- softmax: one pixel per thread (t<256); columns are thread-private
    if (t < 256) {
        const float rn = rn_lds[t];
        float a[64];
        #pragma unroll
        for (int k = 0; k < 64; ++k)
            a[k] = fmaf(buf_f[k * 260 + t], rn, bias_lds[k]);
        float mx = -3.402823466e38f;
        #pragma unroll
        for (int k = 0; k < 64; ++k) mx = fmaxf(mx, a[k]);
        float den = 0.f;
        #pragma unroll
        for (int k = 0; k < 64; ++k) { a[k] = __expf(a[k] - mx); den += a[k]; }
        const float inv = 1.f / den;
        #pragma unroll
        for (int k = 0; k < 64; ++k) {
            const float v = a[k] * inv;
            const unsigned u  = __float_as_uint(v);
            const float hif   = __uint_as_float(u & 0xFFFF0000u);
            const unsigned lo = __float_as_uint(v - hif) >> 16;
            buf[k * 260 + t] = (u & 0xFFFF0000u) | lo;   // (hi<<16)|lo
        }
    }
    __syncthreads();

    // ---- GEMM2: agg += a' @ (x*rn)^T ; asum via MFMA with ones-B
    f32x4 acc2[8];
    #pragma unroll
    for (int i = 0; i < 8; ++i) acc2[i] = f32x4{0.f, 0.f, 0.f, 0.f};
    f32x4 asum_acc = f32x4{0.f, 0.f, 0.f, 0.f};
    const u32x4 ONES = {0x3F803F80u, 0x3F803F80u, 0x3F803F80u, 0x3F803F80u};
    const bool asum_wave = (w < 4);       // waves 0..3 cover mtiles 0..3 exactly once

    for (int ks = 0; ks < 8; ++ks) {
        // A frag: packed a at [k = k0+l15][p = ks*32+cs+j], contiguous 8 dwords
        const unsigned* ap = buf + (k0 + l15) * 260 + ks * 32 + cs;
        const u32x4 pa = *(const u32x4*)ap;
        const u32x4 pb = *(const u32x4*)(ap + 4);
        u32x4 ahi, alo;
        ahi[0] = (pa[1] & 0xFFFF0000u) | (pa[0] >> 16);
        ahi[1] = (pa[3] & 0xFFFF0000u) | (pa[2] >> 16);
        ahi[2] = (pb[1] & 0xFFFF0000u) | (pb[0] >> 16);
        ahi[3] = (pb[3] & 0xFFFF0000u) | (pb[2] >> 16);
        alo[0] = (pa[1] << 16) | (pa[0] & 0xFFFFu);
        alo[1] = (pa[3] << 16) | (pa[2] & 0xFFFFu);
        alo[2] = (pb[1] << 16) | (pb[0] & 0xFFFFu);
        alo[3] = (pb[3] << 16) | (pb[2] & 0xFFFFu);

        const float* rp = rn_lds + ks * 32 + cs;
        const f32x4 r0 = *(const f32x4*)rp;
        const f32x4 r1 = *(const f32x4*)(rp + 4);
        float rnv[8] = {r0[0], r0[1], r0[2], r0[3], r1[0], r1[1], r1[2], r1[3]};

        if (asum_wave) {
            asum_acc = MFMA(as_bf(ahi), as_bf(ONES), asum_acc);
            asum_acc = MFMA(as_bf(alo), as_bf(ONES), asum_acc);
        }
        #pragma unroll
        for (int ntl = 0; ntl < 8; ++ntl) {
            // B frag: x[c = nt*16+l15][p = pbase + ks*32+cs+j] * rn, contiguous 32B
            const float* xp2 = x + ximg + (size_t)((nt0 + ntl) * 16 + l15) * 1024
                               + pbase + ks * 32 + cs;
            const float4 f0 = *(const float4*)xp2;
            const float4 f1 = *(const float4*)(xp2 + 4);
            float xv[8];
            xv[0] = f0.x * rnv[0]; xv[1] = f0.y * rnv[1];
            xv[2] = f0.z * rnv[2]; xv[3] = f0.w * rnv[3];
            xv[4] = f1.x * rnv[4]; xv[5] = f1.y * rnv[5];
            xv[6] = f1.z * rnv[6]; xv[7] = f1.w * rnv[7];
            u32x4 bhi, blo; split8(xv, bhi, blo);
            acc2[ntl] = MFMA(as_bf(ahi), as_bf(bhi), acc2[ntl]);
            acc2[ntl] = MFMA(as_bf(ahi), as_bf(blo), acc2[ntl]);
            acc2[ntl] = MFMA(as_bf(alo), as_bf(bhi), acc2[ntl]);
        }
    }

    // ---- publish partials (4 quarter-blocks per image)
    float* op = out + (size_t)n * 16384;
    #pragma unroll
    for (int ntl = 0; ntl < 8; ++ntl) {
        const int c = (nt0 + ntl) * 16 + l15;
        #pragma unroll
        for (int r = 0; r < 4; ++r)
            atomicAdd(&op[(k0 + lg4 * 4 + r) * 256 + c], acc2[ntl][r]);
    }
    if (asum_wave && l15 == 0) {
        #pragma unroll
        for (int r = 0; r < 4; ++r)
            atomicAdd(&asum_g[n * 64 + k0 + lg4 * 4 + r], asum_acc[r]);
    }
}

__global__ __launch_bounds__(256) void netvlad_epi(
    float* __restrict__ out, const float* __restrict__ asum_g,
    const float* __restrict__ cent) {
    __shared__ float wred[4];
    __shared__ float gs_sh;
    const int n = blockIdx.x;
    const int t = threadIdx.x;
    const int k = t >> 2;          // 4 threads per cluster row
    const int q = t & 3;
    float* op = out + (size_t)n * 16384 + k * 256 + q * 64;
    const float* cp = cent + k * 256 + q * 64;
    const float as = asum_g[n * 64 + k];

    float v[64];
    float ss = 0.f;
    #pragma unroll
    for (int i = 0; i < 64; i += 4) {
        const float4 av = *(const float4*)&op[i];
        const float4 cv = *(const float4*)&cp[i];
        v[i+0] = fmaf(-as, cv.x, av.x);
        v[i+1] = fmaf(-as, cv.y, av.y);
        v[i+2] = fmaf(-as, cv.z, av.z);
        v[i+3] = fmaf(-as, cv.w, av.w);
        ss = fmaf(v[i+0], v[i+0], ss);
        ss = fmaf(v[i+1], v[i+1], ss);
        ss = fmaf(v[i+2], v[i+2], ss);
        ss = fmaf(v[i+3], v[i+3], ss);
    }
    // intra-norm: reduce over the 4 lanes sharing k
    ss += __shfl_xor(ss, 1);
    ss += __shfl_xor(ss, 2);
    const float iscale = 1.f / fmaxf(sqrtf(ss), EPSF);

    // global norm: sum of ss*iscale^2 over distinct k rows
    float g = (q == 0) ? ss * iscale * iscale : 0.f;
    #pragma unroll
    for (int off = 4; off < 64; off <<= 1) g += __shfl_xor(g, off);
    if ((t & 63) == 0) wred[t >> 6] = g;
    __syncthreads();
    if (t == 0) {
        const float tot = wred[0] + wred[1] + wred[2] + wred[3];
        gs_sh = 1.f / fmaxf(sqrtf(tot), EPSF);
    }
    __syncthreads();
    const float fs = iscale * gs_sh;
    #pragma unroll
    for (int i = 0; i < 64; i += 4) {
        float4 w4;
        w4.x = v[i+0] * fs; w4.y = v[i+1] * fs;
        w4.z = v[i+2] * fs; w4.w = v[i+3] * fs;
        *(float4*)&op[i] = w4;
    }
}

extern "C" void kernel_launch(void* const* d_in, const int* in_sizes, int n_in,
                              void* d_out, int out_size, void* d_ws, size_t ws_size,
                              hipStream_t stream) {
    (void)in_sizes; (void)n_in; (void)ws_size;
    const float* x    = (const float*)d_in[0];
    const float* w    = (const float*)d_in[1];
    const float* b    = (const float*)d_in[2];
    const float* cent = (const float*)d_in[3];
    float* out    = (float*)d_out;
    float* asum_g = (float*)d_ws;          // 8192 floats

    hipMemsetAsync(d_out, 0, (size_t)out_size * sizeof(float), stream);
    hipMemsetAsync(asum_g, 0, 128 * 64 * sizeof(float), stream);
    netvlad_mfma<<<512, 512, 0, stream>>>(x, w, b, out, asum_g);
    netvlad_epi<<<128, 256, 0, stream>>>(out, asum_g, cent);
}